// Round 7
// baseline (300.064 us; speedup 1.0000x reference)
//
#include <hip/hip_runtime.h>
#include <hip/hip_bf16.h>

#define DDIM 2048
#define TTIMES 256
#define BM 64
#define BK 64
#define NT 32                 // 2048/64 K-steps
#define THREADS 512

typedef __attribute__((ext_vector_type(8))) short short8;
typedef __attribute__((ext_vector_type(4))) float f32x4;

using gvoid = const __attribute__((address_space(1))) void;
using svoid = __attribute__((address_space(3))) void;

__device__ __forceinline__ void gld16(const void* g, void* l) {
    __builtin_amdgcn_global_load_lds((gvoid*)g, (svoid*)l, 16, 0, 0);
}

__device__ __forceinline__ ushort f2bf(float f) {
    union { float f; unsigned int u; } v; v.f = f;
    unsigned int u = v.u;
    unsigned int r = (u + 0x7FFFu + ((u >> 16) & 1u)) >> 16;   // RNE
    return (ushort)r;
}
__device__ __forceinline__ float bf2f(ushort u) {
    union { unsigned int u; float f; } v; v.u = ((unsigned int)u) << 16;
    return v.f;
}
__device__ __forceinline__ short cvt1(float f) {
    union { __hip_bfloat16 h; ushort u; } cv;
    cv.h = __float2bfloat16(f);          // hardware RNE cvt
    return (short)cv.u;
}

// ---------------- normalize org rows -> bf16 o in workspace ----------------
__global__ void norm_rows(const float* __restrict__ org, ushort* __restrict__ obf) {
    const int a   = blockIdx.x;
    const int tid = threadIdx.x;    // 256 threads
    const float* row = org + (size_t)a * DDIM;
    float4 v0 = ((const float4*)row)[tid * 2];
    float4 v1 = ((const float4*)row)[tid * 2 + 1];
    float s = v0.x*v0.x + v0.y*v0.y + v0.z*v0.z + v0.w*v0.w
            + v1.x*v1.x + v1.y*v1.y + v1.z*v1.z + v1.w*v1.w;
    #pragma unroll
    for (int off = 1; off < 64; off <<= 1) s += __shfl_xor(s, off);
    __shared__ float wsum[4];
    const int lane = tid & 63, w = tid >> 6;
    if (lane == 0) wsum[w] = s;
    __syncthreads();
    const float tot = wsum[0] + wsum[1] + wsum[2] + wsum[3];
    const float scale = 1.0f / fmaxf(sqrtf(tot), 1e-12f);
    union { ushort u[8]; uint4 v; } pk;
    pk.u[0] = f2bf(v0.x * scale); pk.u[1] = f2bf(v0.y * scale);
    pk.u[2] = f2bf(v0.z * scale); pk.u[3] = f2bf(v0.w * scale);
    pk.u[4] = f2bf(v1.x * scale); pk.u[5] = f2bf(v1.y * scale);
    pk.u[6] = f2bf(v1.z * scale); pk.u[7] = f2bf(v1.w * scale);
    ((uint4*)(obf + (size_t)a * DDIM))[tid] = pk.v;
}

// ---- BM=64 x BK=64, A-only LDS (gload_lds), B global->reg, K-staggered ----
// Block: 512 thr = 8 waves (wm 0..1 row-halves of 32, wn 0..3 time-quarters).
// A: fp32 via gld16, 2 x 16 KB dbuf, 256 B contiguous per row per step,
//    XOR chunk swizzle (2-way aliasing = free). B: obf L2-resident, straight
//    global->reg in compute phase (compiler-managed precise vmcnt; STAGE
//    issued BEFORE B loads so B-waits never drain the staging DMA).
__global__ __launch_bounds__(THREADS, 4) void gemm_trace(
    const float* __restrict__ x, const ushort* __restrict__ obf,
    float* __restrict__ part)
{
    __shared__ __align__(16) float Ab[2][BM * BK];   // 2 x 16 KB

    const int tid  = threadIdx.x;
    const int lane = tid & 63;
    const int wid  = tid >> 6;      // 0..7
    const int wm   = wid >> 2;      // 0..1 (row half of 32)
    const int wn   = wid & 3;       // 0..3 (time quarter of 64)
    const int rb   = blockIdx.x;    // 0..31 (row block of 64)
    const int d    = blockIdx.y;    // 0..31 (batch)
    const int t0   = (d * 32 + rb) & (NT - 1);   // K starting phase

    // ---- A staging: 1024 chunks of 16 B; 2 gld16/thread; src pre-swizzled ----
    const char* xp = (const char*)(x + (size_t)d * DDIM * DDIM
                                     + (size_t)rb * BM * DDIM);
    const int v0 = wid * 128 + lane, v1 = v0 + 64;
    const int r0 = v0 >> 4, q0 = (v0 & 15) ^ (r0 & 7);
    const int r1 = v1 >> 4, q1 = (v1 & 15) ^ (r1 & 7);
    const char* as0 = xp + (size_t)r0 * (DDIM * 4) + q0 * 16;
    const char* as1 = xp + (size_t)r1 * (DDIM * 4) + q1 * 16;

#define STAGE(T, buf) do {                                      \
    gld16(as0 + (size_t)(T) * 256, (char*)Ab[buf] + v0 * 16);   \
    gld16(as1 + (size_t)(T) * 256, (char*)Ab[buf] + v1 * 16);   \
} while (0)

    // ---- fragment indexing ----
    const int lr = lane & 15, lq = lane >> 4;
    int arbase[2], arx[2];
    #pragma unroll
    for (int mi = 0; mi < 2; ++mi) {
        const int r = wm * 32 + mi * 16 + lr;
        arbase[mi] = r * BK;
        arx[mi]    = r & 7;
    }
    const ushort* bt = obf + (size_t)(wn * 64 + lr) * DDIM + lq * 8;

    f32x4 acc[2][4];
    #pragma unroll
    for (int mi = 0; mi < 2; ++mi)
        #pragma unroll
        for (int ni = 0; ni < 4; ++ni)
            acc[mi][ni] = (f32x4){0.f, 0.f, 0.f, 0.f};

#define COMPUTE(cur, T) do {                                                \
    _Pragma("unroll")                                                       \
    for (int ss = 0; ss < 2; ++ss) {                                        \
        short8 af[2];                                                       \
        _Pragma("unroll")                                                   \
        for (int mi = 0; mi < 2; ++mi) {                                    \
            const int q = ss * 8 + lq * 2;                                  \
            const float4 lo = *(const float4*)                              \
                &Ab[cur][arbase[mi] + ((q)     ^ arx[mi]) * 4];             \
            const float4 hi = *(const float4*)                              \
                &Ab[cur][arbase[mi] + ((q + 1) ^ arx[mi]) * 4];             \
            short8 a8;                                                      \
            a8[0] = cvt1(lo.x); a8[1] = cvt1(lo.y);                         \
            a8[2] = cvt1(lo.z); a8[3] = cvt1(lo.w);                         \
            a8[4] = cvt1(hi.x); a8[5] = cvt1(hi.y);                         \
            a8[6] = cvt1(hi.z); a8[7] = cvt1(hi.w);                         \
            af[mi] = a8;                                                    \
        }                                                                   \
        short8 bb[4];                                                       \
        _Pragma("unroll")                                                   \
        for (int ni = 0; ni < 4; ++ni)                                      \
            bb[ni] = *(const short8*)(bt + (size_t)ni * 16 * DDIM           \
                                      + (T) * BK + ss * 32);                \
        _Pragma("unroll")                                                   \
        for (int mi = 0; mi < 2; ++mi)                                      \
            _Pragma("unroll")                                               \
            for (int ni = 0; ni < 4; ++ni)                                  \
                acc[mi][ni] = __builtin_amdgcn_mfma_f32_16x16x32_bf16(      \
                    af[mi], bb[ni], acc[mi][ni], 0, 0, 0);                  \
    }                                                                       \
} while (0)

    // ---- prologue ----
    STAGE(t0, 0);

    #pragma unroll 1
    for (int t = 0; t < NT - 1; ++t) {
        const int cur = t & 1;
        const int T  = (t0 + t) & (NT - 1);
        const int Tn = (t0 + t + 1) & (NT - 1);
        STAGE(Tn, cur ^ 1);                                // in flight across barrier
        asm volatile("s_waitcnt vmcnt(2)" ::: "memory");   // tile t's DMA done
        __builtin_amdgcn_sched_barrier(0);
        __builtin_amdgcn_s_barrier();                      // all waves' DMA visible
        __builtin_amdgcn_sched_barrier(0);
        COMPUTE(cur, T);
        __builtin_amdgcn_sched_barrier(0);
        __builtin_amdgcn_s_barrier();                      // reads done; buf free
        __builtin_amdgcn_sched_barrier(0);
    }
    // last step
    {
        asm volatile("s_waitcnt vmcnt(0)" ::: "memory");
        __builtin_amdgcn_sched_barrier(0);
        __builtin_amdgcn_s_barrier();
        __builtin_amdgcn_sched_barrier(0);
        COMPUTE((NT - 1) & 1, (t0 + NT - 1) & (NT - 1));
    }
    __syncthreads();

#undef STAGE
#undef COMPUTE

    // ---- fused trace epilogue ----
    // acc[mi][ni][j]: row = rb*64 + wm*32 + mi*16 + lq*4 + j,
    //                 time = wn*64 + ni*16 + lr
    float* plds = (float*)&Ab[0][0];   // 2 x 256 floats

    #pragma unroll
    for (int ni = 0; ni < 4; ++ni) {
        const int a_idx = wn * 64 + ni * 16 + lr;
        float ps = 0.f;
        #pragma unroll
        for (int mi = 0; mi < 2; ++mi) {
            const int bg = rb * BM + wm * 32 + mi * 16 + lq * 4;
            const ushort4 w = *(const ushort4*)(obf + (size_t)a_idx * DDIM + bg);
            ps += bf2f(w.x) * acc[mi][ni][0];
            ps += bf2f(w.y) * acc[mi][ni][1];
            ps += bf2f(w.z) * acc[mi][ni][2];
            ps += bf2f(w.w) * acc[mi][ni][3];
        }
        ps += __shfl_xor(ps, 16);
        ps += __shfl_xor(ps, 32);
        if (lane < 16) plds[wm * 256 + a_idx] = ps;
    }
    __syncthreads();
    if (tid < 256)
        part[((size_t)d * 32 + rb) * TTIMES + tid] = plds[tid] + plds[256 + tid];
}

// ---------------- final reduce over row-blocks ----------------
__global__ void reduce_part(const float* __restrict__ part, float* __restrict__ out) {
    const int d = blockIdx.x;    // 32
    const int a = threadIdx.x;   // 256
    float s = 0.f;
    #pragma unroll
    for (int rb = 0; rb < 32; ++rb)
        s += part[((size_t)d * 32 + rb) * TTIMES + a];
    out[(size_t)d * TTIMES + a] = s;
}

extern "C" void kernel_launch(void* const* d_in, const int* in_sizes, int n_in,
                              void* d_out, int out_size, void* d_ws, size_t ws_size,
                              hipStream_t stream) {
    const float* x   = (const float*)d_in[0];   // (32, 2048, 2048) fp32
    const float* org = (const float*)d_in[1];   // (256, 2048) fp32
    float* out = (float*)d_out;                 // (32, 256) fp32

    ushort* obf = (ushort*)d_ws;                          // 1 MiB bf16 normalized o
    float*  prt = (float*)((char*)d_ws + (1 << 20));      // 1 MiB partials (32x32x256)

    norm_rows<<<dim3(TTIMES), dim3(256), 0, stream>>>(org, obf);
    gemm_trace<<<dim3(32, 32), dim3(THREADS), 0, stream>>>(x, obf, prt);
    reduce_part<<<dim3(32), dim3(256), 0, stream>>>(prt, out);
}

// Round 10
// 133.414 us; speedup vs baseline: 2.2491x; 2.2491x over previous
//
#include <hip/hip_runtime.h>
#include <hip/hip_bf16.h>

#define DDIM 2048
#define TTIMES 256
#define NT 64                 // K-steps of 32
#define THREADS 512

typedef __attribute__((ext_vector_type(8))) short short8;
typedef __attribute__((ext_vector_type(4))) float f32x4;

using gvoid = const __attribute__((address_space(1))) void;
using svoid = __attribute__((address_space(3))) void;

__device__ __forceinline__ void gld16(const void* g, void* l) {
    __builtin_amdgcn_global_load_lds((gvoid*)g, (svoid*)l, 16, 0, 0);
}

__device__ __forceinline__ ushort f2bf(float f) {
    union { float f; unsigned int u; } v; v.f = f;
    unsigned int u = v.u;
    unsigned int r = (u + 0x7FFFu + ((u >> 16) & 1u)) >> 16;   // RNE
    return (ushort)r;
}
__device__ __forceinline__ float bf2f(ushort u) {
    union { unsigned int u; float f; } v; v.u = ((unsigned int)u) << 16;
    return v.f;
}
__device__ __forceinline__ short cvt1(float f) {
    union { __hip_bfloat16 h; ushort u; } cv;
    cv.h = __float2bfloat16(f);          // hardware RNE cvt
    return (short)cv.u;
}

// ---------------- normalize org rows -> bf16 o in workspace ----------------
__global__ void norm_rows(const float* __restrict__ org, ushort* __restrict__ obf) {
    const int a   = blockIdx.x;     // time row
    const int tid = threadIdx.x;    // 256 threads
    const float* row = org + (size_t)a * DDIM;
    float4 v0 = ((const float4*)row)[tid * 2];
    float4 v1 = ((const float4*)row)[tid * 2 + 1];
    float s = v0.x*v0.x + v0.y*v0.y + v0.z*v0.z + v0.w*v0.w
            + v1.x*v1.x + v1.y*v1.y + v1.z*v1.z + v1.w*v1.w;
    #pragma unroll
    for (int off = 1; off < 64; off <<= 1) s += __shfl_xor(s, off);
    __shared__ float wsum[4];
    const int lane = tid & 63, w = tid >> 6;
    if (lane == 0) wsum[w] = s;
    __syncthreads();
    const float tot = wsum[0] + wsum[1] + wsum[2] + wsum[3];
    const float scale = 1.0f / fmaxf(sqrtf(tot), 1e-12f);
    union { ushort u[8]; uint4 v; } pk;
    pk.u[0] = f2bf(v0.x * scale); pk.u[1] = f2bf(v0.y * scale);
    pk.u[2] = f2bf(v0.z * scale); pk.u[3] = f2bf(v0.w * scale);
    pk.u[4] = f2bf(v1.x * scale); pk.u[5] = f2bf(v1.y * scale);
    pk.u[6] = f2bf(v1.z * scale); pk.u[7] = f2bf(v1.w * scale);
    ((uint4*)(obf + (size_t)a * DDIM))[tid] = pk.v;
}

// ---- depth-2 A-prefetch (3 bufs) + B double-buffer, all gload_lds DMA ----
// R6 structure/formulas exactly; only the buffer depth and vmcnt ledger change.
// Steady step t: issue B(t+1), A(t+2); vmcnt(6) retires A(t),B(t) while
// A(t+1),B(t+1),A(t+2) stay in flight (A has 2 full steps of HBM lead).
// LDS 3x16 + 2x16 = 80 KB -> exactly 2 blocks/CU.
__global__ __launch_bounds__(THREADS, 4) void gemm_trace(
    const float* __restrict__ x, const ushort* __restrict__ obf,
    float* __restrict__ part)
{
    __shared__ __align__(16) char Ab[3][16384];   // fp32 A tiles: 128 rows x 32 k
    __shared__ __align__(16) char Bb[2][16384];   // bf16 B tiles: 256 rows x 32 k

    const int tid  = threadIdx.x;
    const int lane = tid & 63;
    const int wid  = tid >> 6;      // 0..7
    const int wm   = wid >> 2;      // 0..1 (row half)
    const int wn   = wid & 3;       // 0..3 (time quarter)
    const int rb   = blockIdx.x;    // 0..15 (row block of 128)
    const int d    = blockIdx.y;    // 0..31 (batch)
    const int t0   = (d * 16 + rb) & (NT - 1);   // K stagger phase
#define W(n) ((t0 + (n)) & (NT - 1))

    const char* ab = (const char*)(x + (size_t)d * DDIM * DDIM + (size_t)rb * 128 * DDIM);
    const char* bb = (const char*)obf;

    // staging: A 1024 chunks (128 rows x 8), B 1024 chunks (256 rows x 4); 2 each/thread
    const int ar0 = tid >> 3,         aq0 = ((tid & 7) ^ (ar0 & 7)) * 16;
    const int ar1 = (tid + 512) >> 3, aq1 = (((tid + 512) & 7) ^ (ar1 & 7)) * 16;
    const int br0 = tid >> 2,         bq0 = ((tid & 3) ^ (br0 & 3)) * 16;
    const int br1 = (tid + 512) >> 2, bq1 = (((tid + 512) & 3) ^ (br1 & 3)) * 16;

    const char* as0 = ab + (size_t)ar0 * (DDIM * 4) + aq0;
    const char* as1 = ab + (size_t)ar1 * (DDIM * 4) + aq1;
    const char* bs0 = bb + (size_t)br0 * (DDIM * 2) + bq0;
    const char* bs1 = bb + (size_t)br1 * (DDIM * 2) + bq1;

#define STAGE_A(t, buf) do {                                  \
    gld16(as0 + (t) * 128, &Ab[buf][tid * 16]);               \
    gld16(as1 + (t) * 128, &Ab[buf][(tid + 512) * 16]);       \
} while (0)
#define STAGE_B(t, buf) do {                                  \
    gld16(bs0 + (t) * 64,  &Bb[buf][tid * 16]);               \
    gld16(bs1 + (t) * 64,  &Bb[buf][(tid + 512) * 16]);       \
} while (0)

    const int lr = lane & 15;       // row-in-16 (A) / time-in-16 (B)
    const int lq = lane >> 4;       // k-quarter

    int aoff0[4], aoff1[4], boff[4];
    #pragma unroll
    for (int mi = 0; mi < 4; ++mi) {
        const int r = wm * 64 + mi * 16 + lr;
        aoff0[mi] = r * 128 + ((2 * lq)     ^ (r & 7)) * 16;
        aoff1[mi] = r * 128 + ((2 * lq + 1) ^ (r & 7)) * 16;
    }
    #pragma unroll
    for (int ni = 0; ni < 4; ++ni) {
        const int rt = wn * 64 + ni * 16 + lr;
        boff[ni] = rt * 64 + (lq ^ (rt & 3)) * 16;
    }

    f32x4 acc[4][4];
    #pragma unroll
    for (int mi = 0; mi < 4; ++mi)
        #pragma unroll
        for (int ni = 0; ni < 4; ++ni)
            acc[mi][ni] = (f32x4){0.f, 0.f, 0.f, 0.f};

#define COMPUTE(abuf, bbuf) do {                                            \
    short8 af[4], bfr[4];                                                   \
    _Pragma("unroll")                                                       \
    for (int mi = 0; mi < 4; ++mi) {                                        \
        const float4 lo = *(const float4*)&Ab[abuf][aoff0[mi]];             \
        const float4 hi = *(const float4*)&Ab[abuf][aoff1[mi]];             \
        short8 a8;                                                          \
        a8[0] = cvt1(lo.x); a8[1] = cvt1(lo.y);                             \
        a8[2] = cvt1(lo.z); a8[3] = cvt1(lo.w);                             \
        a8[4] = cvt1(hi.x); a8[5] = cvt1(hi.y);                             \
        a8[6] = cvt1(hi.z); a8[7] = cvt1(hi.w);                             \
        af[mi] = a8;                                                        \
    }                                                                       \
    _Pragma("unroll")                                                       \
    for (int ni = 0; ni < 4; ++ni)                                          \
        bfr[ni] = *(const short8*)&Bb[bbuf][boff[ni]];                      \
    _Pragma("unroll")                                                       \
    for (int mi = 0; mi < 4; ++mi)                                          \
        _Pragma("unroll")                                                   \
        for (int ni = 0; ni < 4; ++ni)                                      \
            acc[mi][ni] = __builtin_amdgcn_mfma_f32_16x16x32_bf16(          \
                af[mi], bfr[ni], acc[mi][ni], 0, 0, 0);                     \
} while (0)

#define VMW(n) do {                                                         \
    asm volatile("s_waitcnt vmcnt(" #n ")" ::: "memory");                   \
    __builtin_amdgcn_sched_barrier(0); } while (0)
#define SBAR do {                                                           \
    __builtin_amdgcn_sched_barrier(0);                                      \
    __builtin_amdgcn_s_barrier();                                           \
    __builtin_amdgcn_sched_barrier(0); } while (0)
#define LGBAR do {                                                          \
    __builtin_amdgcn_sched_barrier(0);                                      \
    asm volatile("s_waitcnt lgkmcnt(0)" ::: "memory");                      \
    __builtin_amdgcn_s_barrier();                                           \
    __builtin_amdgcn_sched_barrier(0); } while (0)

    // ---- prologue: A(0)->0, B(0)->0, A(1)->1 ----
    STAGE_A(W(0), 0);
    STAGE_B(W(0), 0);
    STAGE_A(W(1), 1);

    int abf = 0;                   // t % 3 at loop top
    #pragma unroll 1
    for (int t = 0; t < NT - 2; ++t) {
        STAGE_B(W(t + 1), (t + 1) & 1);
        int ab2 = abf + 2; if (ab2 >= 3) ab2 -= 3;
        STAGE_A(W(t + 2), ab2);
        VMW(6);                    // retire A(t), B(t); keep A(t+1),B(t+1),A(t+2)
        SBAR;                      // tile t visible to all waves
        COMPUTE(abf, t & 1);
        LGBAR;                     // reads done -> next step may overwrite
        ++abf; if (abf == 3) abf = 0;
    }
    // ---- t = 62 (abf == 2): stage B(63) only ----
    STAGE_B(W(63), 1);
    VMW(4);                        // retire A(62), B(62)
    SBAR;
    COMPUTE(2, 0);
    LGBAR;
    // ---- t = 63 ----
    VMW(0);
    SBAR;
    COMPUTE(0, 1);
    __syncthreads();

#undef W
#undef STAGE_A
#undef STAGE_B
#undef COMPUTE
#undef VMW
#undef SBAR
#undef LGBAR

    // ---- fused trace epilogue ----
    // acc[mi][ni][j]: row = rb*128 + wm*64 + mi*16 + lq*4 + j, time = wn*64 + ni*16 + lr
    float* plds = (float*)&Ab[0][0];   // 2 x 256 floats (LDS free now)

    #pragma unroll
    for (int ni = 0; ni < 4; ++ni) {
        const int a_idx = wn * 64 + ni * 16 + lr;
        float ps = 0.f;
        #pragma unroll
        for (int mi = 0; mi < 4; ++mi) {
            const int bg = rb * 128 + wm * 64 + mi * 16 + lq * 4;
            const ushort4 w = *(const ushort4*)(obf + (size_t)a_idx * DDIM + bg);
            ps += bf2f(w.x) * acc[mi][ni][0];
            ps += bf2f(w.y) * acc[mi][ni][1];
            ps += bf2f(w.z) * acc[mi][ni][2];
            ps += bf2f(w.w) * acc[mi][ni][3];
        }
        ps += __shfl_xor(ps, 16);
        ps += __shfl_xor(ps, 32);
        if (lane < 16) plds[wm * 256 + a_idx] = ps;
    }
    __syncthreads();
    if (tid < 256)
        part[((size_t)d * 16 + rb) * TTIMES + tid] = plds[tid] + plds[256 + tid];
}

// ---------------- final reduce over row-blocks ----------------
__global__ void reduce_part(const float* __restrict__ part, float* __restrict__ out) {
    const int d = blockIdx.x;    // 32
    const int a = threadIdx.x;   // 256
    float s = 0.f;
    #pragma unroll
    for (int rb = 0; rb < 16; ++rb)
        s += part[((size_t)d * 16 + rb) * TTIMES + a];
    out[(size_t)d * TTIMES + a] = s;
}

extern "C" void kernel_launch(void* const* d_in, const int* in_sizes, int n_in,
                              void* d_out, int out_size, void* d_ws, size_t ws_size,
                              hipStream_t stream) {
    const float* x   = (const float*)d_in[0];   // (32, 2048, 2048) fp32
    const float* org = (const float*)d_in[1];   // (256, 2048) fp32
    float* out = (float*)d_out;                 // (32, 256) fp32

    ushort* obf = (ushort*)d_ws;                          // 1 MiB bf16 normalized o
    float*  prt = (float*)((char*)d_ws + (1 << 20));      // 512 KiB partials (32x16x256)

    norm_rows<<<dim3(TTIMES), dim3(256), 0, stream>>>(org, obf);
    gemm_trace<<<dim3(16, 32), dim3(THREADS), 0, stream>>>(x, obf, prt);
    reduce_part<<<dim3(32), dim3(256), 0, stream>>>(prt, out);
}

// Round 11
// 129.921 us; speedup vs baseline: 2.3096x; 1.0269x over previous
//
#include <hip/hip_runtime.h>
#include <hip/hip_bf16.h>

#define DDIM 2048
#define TTIMES 256
#define NT 64                 // K-steps of 32
#define THREADS 512

typedef __attribute__((ext_vector_type(8))) short short8;
typedef __attribute__((ext_vector_type(4))) float f32x4;

using gvoid = const __attribute__((address_space(1))) void;
using svoid = __attribute__((address_space(3))) void;

__device__ __forceinline__ void gld16(const void* g, void* l) {
    __builtin_amdgcn_global_load_lds((gvoid*)g, (svoid*)l, 16, 0, 0);
}

__device__ __forceinline__ ushort f2bf(float f) {
    union { float f; unsigned int u; } v; v.f = f;
    unsigned int u = v.u;
    unsigned int r = (u + 0x7FFFu + ((u >> 16) & 1u)) >> 16;   // RNE
    return (ushort)r;
}
__device__ __forceinline__ float bf2f(ushort u) {
    union { unsigned int u; float f; } v; v.u = ((unsigned int)u) << 16;
    return v.f;
}
__device__ __forceinline__ short cvt1(float f) {
    union { __hip_bfloat16 h; ushort u; } cv;
    cv.h = __float2bfloat16(f);          // hardware RNE cvt
    return (short)cv.u;
}

// ---------------- normalize org rows -> bf16 o in workspace ----------------
__global__ void norm_rows(const float* __restrict__ org, ushort* __restrict__ obf) {
    const int a   = blockIdx.x;     // time row
    const int tid = threadIdx.x;    // 256 threads
    const float* row = org + (size_t)a * DDIM;
    float4 v0 = ((const float4*)row)[tid * 2];
    float4 v1 = ((const float4*)row)[tid * 2 + 1];
    float s = v0.x*v0.x + v0.y*v0.y + v0.z*v0.z + v0.w*v0.w
            + v1.x*v1.x + v1.y*v1.y + v1.z*v1.z + v1.w*v1.w;
    #pragma unroll
    for (int off = 1; off < 64; off <<= 1) s += __shfl_xor(s, off);
    __shared__ float wsum[4];
    const int lane = tid & 63, w = tid >> 6;
    if (lane == 0) wsum[w] = s;
    __syncthreads();
    const float tot = wsum[0] + wsum[1] + wsum[2] + wsum[3];
    const float scale = 1.0f / fmaxf(sqrtf(tot), 1e-12f);
    union { ushort u[8]; uint4 v; } pk;
    pk.u[0] = f2bf(v0.x * scale); pk.u[1] = f2bf(v0.y * scale);
    pk.u[2] = f2bf(v0.z * scale); pk.u[3] = f2bf(v0.w * scale);
    pk.u[4] = f2bf(v1.x * scale); pk.u[5] = f2bf(v1.y * scale);
    pk.u[6] = f2bf(v1.z * scale); pk.u[7] = f2bf(v1.w * scale);
    ((uint4*)(obf + (size_t)a * DDIM))[tid] = pk.v;
}

// ---- ONE barrier per K-step: A 3-deep, B 2-deep, all gload_lds DMA ----
// Per iter t: vmcnt(2) retires exactly tile t (keeps A(t+1) flying);
// barrier proves compute(t-1) reads done -> staging B(t+1)/A(t+2) post-barrier
// is race-free (targets disjoint mod3/mod2 from compute(t) reads).
// A(t+1),A(t+2): 2-step HBM lead; B(t+1): 1-step lead (obf L2-resident).
// LDS 3x16 + 2x16 = 80 KB -> exactly 2 blocks/CU.
__global__ __launch_bounds__(THREADS, 4) void gemm_trace(
    const float* __restrict__ x, const ushort* __restrict__ obf,
    float* __restrict__ part)
{
    __shared__ __align__(16) char Ab[3][16384];   // fp32 A tiles: 128 rows x 32 k
    __shared__ __align__(16) char Bb[2][16384];   // bf16 B tiles: 256 rows x 32 k

    const int tid  = threadIdx.x;
    const int lane = tid & 63;
    const int wid  = tid >> 6;      // 0..7
    const int wm   = wid >> 2;      // 0..1 (row half)
    const int wn   = wid & 3;       // 0..3 (time quarter)
    const int rb   = blockIdx.x;    // 0..15 (row block of 128)
    const int d    = blockIdx.y;    // 0..31 (batch)
    const int t0   = (d * 16 + rb) & (NT - 1);   // K stagger phase
#define W(n) ((t0 + (n)) & (NT - 1))

    const char* ab = (const char*)(x + (size_t)d * DDIM * DDIM + (size_t)rb * 128 * DDIM);
    const char* bb = (const char*)obf;

    // staging: A 1024 chunks (128 rows x 8), B 1024 chunks (256 rows x 4); 2 each/thread
    const int ar0 = tid >> 3,         aq0 = ((tid & 7) ^ (ar0 & 7)) * 16;
    const int ar1 = (tid + 512) >> 3, aq1 = (((tid + 512) & 7) ^ (ar1 & 7)) * 16;
    const int br0 = tid >> 2,         bq0 = ((tid & 3) ^ (br0 & 3)) * 16;
    const int br1 = (tid + 512) >> 2, bq1 = (((tid + 512) & 3) ^ (br1 & 3)) * 16;

    const char* as0 = ab + (size_t)ar0 * (DDIM * 4) + aq0;
    const char* as1 = ab + (size_t)ar1 * (DDIM * 4) + aq1;
    const char* bs0 = bb + (size_t)br0 * (DDIM * 2) + bq0;
    const char* bs1 = bb + (size_t)br1 * (DDIM * 2) + bq1;

#define STAGE_A(t, buf) do {                                  \
    gld16(as0 + (t) * 128, &Ab[buf][tid * 16]);               \
    gld16(as1 + (t) * 128, &Ab[buf][(tid + 512) * 16]);       \
} while (0)
#define STAGE_B(t, buf) do {                                  \
    gld16(bs0 + (t) * 64,  &Bb[buf][tid * 16]);               \
    gld16(bs1 + (t) * 64,  &Bb[buf][(tid + 512) * 16]);       \
} while (0)

    const int lr = lane & 15;       // row-in-16 (A) / time-in-16 (B)
    const int lq = lane >> 4;       // k-quarter

    int aoff0[4], aoff1[4], boff[4];
    #pragma unroll
    for (int mi = 0; mi < 4; ++mi) {
        const int r = wm * 64 + mi * 16 + lr;
        aoff0[mi] = r * 128 + ((2 * lq)     ^ (r & 7)) * 16;
        aoff1[mi] = r * 128 + ((2 * lq + 1) ^ (r & 7)) * 16;
    }
    #pragma unroll
    for (int ni = 0; ni < 4; ++ni) {
        const int rt = wn * 64 + ni * 16 + lr;
        boff[ni] = rt * 64 + (lq ^ (rt & 3)) * 16;
    }

    f32x4 acc[4][4];
    #pragma unroll
    for (int mi = 0; mi < 4; ++mi)
        #pragma unroll
        for (int ni = 0; ni < 4; ++ni)
            acc[mi][ni] = (f32x4){0.f, 0.f, 0.f, 0.f};

#define COMPUTE(abuf, bbuf) do {                                            \
    short8 af[4], bfr[4];                                                   \
    _Pragma("unroll")                                                       \
    for (int mi = 0; mi < 4; ++mi) {                                        \
        const float4 lo = *(const float4*)&Ab[abuf][aoff0[mi]];             \
        const float4 hi = *(const float4*)&Ab[abuf][aoff1[mi]];             \
        short8 a8;                                                          \
        a8[0] = cvt1(lo.x); a8[1] = cvt1(lo.y);                             \
        a8[2] = cvt1(lo.z); a8[3] = cvt1(lo.w);                             \
        a8[4] = cvt1(hi.x); a8[5] = cvt1(hi.y);                             \
        a8[6] = cvt1(hi.z); a8[7] = cvt1(hi.w);                             \
        af[mi] = a8;                                                        \
    }                                                                       \
    _Pragma("unroll")                                                       \
    for (int ni = 0; ni < 4; ++ni)                                          \
        bfr[ni] = *(const short8*)&Bb[bbuf][boff[ni]];                      \
    _Pragma("unroll")                                                       \
    for (int mi = 0; mi < 4; ++mi)                                          \
        _Pragma("unroll")                                                   \
        for (int ni = 0; ni < 4; ++ni)                                      \
            acc[mi][ni] = __builtin_amdgcn_mfma_f32_16x16x32_bf16(          \
                af[mi], bfr[ni], acc[mi][ni], 0, 0, 0);                     \
} while (0)

#define VMW(n) do {                                                         \
    asm volatile("s_waitcnt vmcnt(" #n ")" ::: "memory");                   \
    __builtin_amdgcn_sched_barrier(0); } while (0)
#define SBAR do {                                                           \
    __builtin_amdgcn_sched_barrier(0);                                      \
    asm volatile("s_waitcnt lgkmcnt(0)" ::: "memory");                      \
    __builtin_amdgcn_s_barrier();                                           \
    __builtin_amdgcn_sched_barrier(0); } while (0)

    // ---- prologue: A(0)->0, B(0)->0, A(1)->1 ----
    STAGE_A(W(0), 0);
    STAGE_B(W(0), 0);
    STAGE_A(W(1), 1);

    int abf = 0;                   // t % 3 at loop top
    #pragma unroll 1
    for (int t = 0; t < NT - 1; ++t) {
        VMW(2);                    // retire A(t)+B(t); keep A(t+1) in flight
        SBAR;                      // compute(t-1) reads proven done
        STAGE_B(W(t + 1), (t + 1) & 1);
        if (t + 2 < NT) {
            int ab2 = abf + 2; if (ab2 >= 3) ab2 -= 3;
            STAGE_A(W(t + 2), ab2);
        }
        COMPUTE(abf, t & 1);
        ++abf; if (abf == 3) abf = 0;
    }
    // ---- last step t = NT-1 ----
    VMW(0);
    SBAR;
    COMPUTE(abf, (NT - 1) & 1);
    __syncthreads();

#undef W
#undef STAGE_A
#undef STAGE_B
#undef COMPUTE
#undef VMW
#undef SBAR

    // ---- fused trace epilogue ----
    // acc[mi][ni][j]: row = rb*128 + wm*64 + mi*16 + lq*4 + j, time = wn*64 + ni*16 + lr
    float* plds = (float*)&Ab[0][0];   // 2 x 256 floats (LDS free now)

    #pragma unroll
    for (int ni = 0; ni < 4; ++ni) {
        const int a_idx = wn * 64 + ni * 16 + lr;
        float ps = 0.f;
        #pragma unroll
        for (int mi = 0; mi < 4; ++mi) {
            const int bg = rb * 128 + wm * 64 + mi * 16 + lq * 4;
            const ushort4 w = *(const ushort4*)(obf + (size_t)a_idx * DDIM + bg);
            ps += bf2f(w.x) * acc[mi][ni][0];
            ps += bf2f(w.y) * acc[mi][ni][1];
            ps += bf2f(w.z) * acc[mi][ni][2];
            ps += bf2f(w.w) * acc[mi][ni][3];
        }
        ps += __shfl_xor(ps, 16);
        ps += __shfl_xor(ps, 32);
        if (lane < 16) plds[wm * 256 + a_idx] = ps;
    }
    __syncthreads();
    if (tid < 256)
        part[((size_t)d * 16 + rb) * TTIMES + tid] = plds[tid] + plds[256 + tid];
}

// ---------------- final reduce over row-blocks ----------------
__global__ void reduce_part(const float* __restrict__ part, float* __restrict__ out) {
    const int d = blockIdx.x;    // 32
    const int a = threadIdx.x;   // 256
    float s = 0.f;
    #pragma unroll
    for (int rb = 0; rb < 16; ++rb)
        s += part[((size_t)d * 16 + rb) * TTIMES + a];
    out[(size_t)d * TTIMES + a] = s;
}

extern "C" void kernel_launch(void* const* d_in, const int* in_sizes, int n_in,
                              void* d_out, int out_size, void* d_ws, size_t ws_size,
                              hipStream_t stream) {
    const float* x   = (const float*)d_in[0];   // (32, 2048, 2048) fp32
    const float* org = (const float*)d_in[1];   // (256, 2048) fp32
    float* out = (float*)d_out;                 // (32, 256) fp32

    ushort* obf = (ushort*)d_ws;                          // 1 MiB bf16 normalized o
    float*  prt = (float*)((char*)d_ws + (1 << 20));      // 512 KiB partials (32x16x256)

    norm_rows<<<dim3(TTIMES), dim3(256), 0, stream>>>(org, obf);
    gemm_trace<<<dim3(16, 32), dim3(THREADS), 0, stream>>>(x, obf, prt);
    reduce_part<<<dim3(32), dim3(256), 0, stream>>>(prt, out);
}